// Round 1
// baseline (222.892 us; speedup 1.0000x reference)
//
#include <hip/hip_runtime.h>
#include <hip/hip_bf16.h>
#include <stdint.h>

typedef __bf16 bf16x8 __attribute__((ext_vector_type(8)));
typedef float f32x4 __attribute__((ext_vector_type(4)));

#define GLB_AS __attribute__((address_space(1)))
#define LDS_AS __attribute__((address_space(3)))

__device__ __forceinline__ void gload_lds16(const void* g, void* l) {
    // dest is wave-uniform base; HW writes base + lane*16
    __builtin_amdgcn_global_load_lds((GLB_AS void*)(g), (LDS_AS void*)(l), 16, 0, 0);
}

// ---------------------------------------------------------------------------
// Kernel 1: row L2-normalize (x gets +1e-7 first), write bf16.
// rows 0..8191 -> x, rows 8192..16383 -> ref. 1024 elems/row, 256 thr, 4/thr.
// ---------------------------------------------------------------------------
__global__ __launch_bounds__(256) void normalize_rows(
    const float* __restrict__ x, const float* __restrict__ ref,
    __bf16* __restrict__ outA, __bf16* __restrict__ outB)
{
    const int row = blockIdx.x;
    const bool isX = row < 8192;
    const size_t r = isX ? (size_t)row : (size_t)(row - 8192);
    const float* src = isX ? (x + r * 1024) : (ref + r * 1024);
    __bf16* dst = isX ? (outA + r * 1024) : (outB + r * 1024);
    const float eps = isX ? 1e-7f : 0.0f;

    const int t = threadIdx.x;
    float4 v = reinterpret_cast<const float4*>(src)[t];
    v.x += eps; v.y += eps; v.z += eps; v.w += eps;
    float ss = v.x * v.x + v.y * v.y + v.z * v.z + v.w * v.w;

    #pragma unroll
    for (int o = 32; o; o >>= 1) ss += __shfl_xor(ss, o, 64);

    __shared__ float red[4];
    const int wave = t >> 6, lane = t & 63;
    if (lane == 0) red[wave] = ss;
    __syncthreads();
    const float tot = red[0] + red[1] + red[2] + red[3];
    const float inv = rsqrtf(fmaxf(tot, 1e-12f));

    __bf16 b[4];
    b[0] = (__bf16)(v.x * inv);
    b[1] = (__bf16)(v.y * inv);
    b[2] = (__bf16)(v.z * inv);
    b[3] = (__bf16)(v.w * inv);
    uint2 pk;
    __builtin_memcpy(&pk, b, 8);
    reinterpret_cast<uint2*>(dst)[t] = pk;
}

// ---------------------------------------------------------------------------
// Kernel 2: C[8192][8192] f32 = A[8192][1024]bf16 . B[8192][1024]bf16 ^T
// m97 structure: 128x128 tile, BK=64, 4 waves (2x2), 16x16x32 bf16 MFMA,
// global_load_lds width-16 into linear LDS, 2 barriers per K-step.
// ---------------------------------------------------------------------------
#define GM 8192
#define GN 8192
#define GK 1024
#define BM 128
#define BN 128
#define BK 64

__global__ __launch_bounds__(256) void gemm_bt(
    const __bf16* __restrict__ A, const __bf16* __restrict__ B,
    float* __restrict__ C)
{
    __shared__ __bf16 As[BM][BK];   // 16 KB
    __shared__ __bf16 Bs[BN][BK];   // 16 KB

    // XCD-bijective swizzle (nwg = 4096, % 8 == 0) then 8x8 supertile.
    const int nwg = gridDim.x;
    const int cpx = nwg >> 3;
    const int bid = blockIdx.x;
    const int swz = (bid & 7) * cpx + (bid >> 3);
    const int super = swz >> 6, within = swz & 63;
    const int tm = ((super & 7) << 3) + (within & 7);   // 0..63
    const int tn = ((super >> 3) << 3) + (within >> 3); // 0..63

    const int tid = threadIdx.x;
    const int wave = tid >> 6;
    const int lane = tid & 63;
    const int wr = wave >> 1;   // wave row 0..1
    const int wc = wave & 1;    // wave col 0..1

    const size_t rowA0 = (size_t)tm * BM;
    const size_t rowB0 = (size_t)tn * BN;

    // staging geometry: 1 KB per wave-issue = 8 rows x 128 B
    const int crow  = lane >> 3;          // row within 8-row chunk
    const int cbyte = (lane & 7) * 16;    // byte offset within 128 B row

    f32x4 acc[4][4] = {};

    #pragma unroll 1
    for (int kt = 0; kt < GK; kt += BK) {
        // ---- stage A and B tiles (each wave: 4 chunks of A, 4 of B) ----
        #pragma unroll
        for (int i = 0; i < 4; ++i) {
            const int c = wave * 4 + i;                 // chunk 0..15
            const char* srcA = (const char*)A +
                ((rowA0 + c * 8 + crow) * (size_t)GK + kt) * 2 + cbyte;
            gload_lds16(srcA, &As[c * 8][0]);
            const char* srcB = (const char*)B +
                ((rowB0 + c * 8 + crow) * (size_t)GK + kt) * 2 + cbyte;
            gload_lds16(srcB, &Bs[c * 8][0]);
        }
        __syncthreads();   // compiler drains vmcnt(0) before barrier

        // ---- compute: 2 k-slices x (4 A-frags, 4 B-frags, 16 MFMA) ----
        #pragma unroll
        for (int ks = 0; ks < 2; ++ks) {
            bf16x8 af[4], bfr[4];
            #pragma unroll
            for (int m = 0; m < 4; ++m)
                af[m] = *reinterpret_cast<const bf16x8*>(
                    &As[wr * 64 + m * 16 + (lane & 15)][ks * 32 + (lane >> 4) * 8]);
            #pragma unroll
            for (int n = 0; n < 4; ++n)
                bfr[n] = *reinterpret_cast<const bf16x8*>(
                    &Bs[wc * 64 + n * 16 + (lane & 15)][ks * 32 + (lane >> 4) * 8]);
            #pragma unroll
            for (int m = 0; m < 4; ++m)
                #pragma unroll
                for (int n = 0; n < 4; ++n)
                    acc[m][n] = __builtin_amdgcn_mfma_f32_16x16x32_bf16(
                        af[m], bfr[n], acc[m][n], 0, 0, 0);
        }
        __syncthreads();   // all reads done before next stage overwrites
    }

    // ---- epilogue: C/D layout col = lane&15, row = (lane>>4)*4 + j ----
    const size_t crow0 = rowA0 + wr * 64;
    const size_t ccol0 = rowB0 + wc * 64;
    #pragma unroll
    for (int m = 0; m < 4; ++m) {
        #pragma unroll
        for (int n = 0; n < 4; ++n) {
            const size_t col = ccol0 + n * 16 + (lane & 15);
            const size_t rbase = crow0 + m * 16 + (lane >> 4) * 4;
            #pragma unroll
            for (int j = 0; j < 4; ++j)
                C[(rbase + j) * (size_t)GN + col] = acc[m][n][j];
        }
    }
}

// ---------------------------------------------------------------------------
// Fallback (only if d_ws is too small): naive fp32, correct but slow.
// ---------------------------------------------------------------------------
__global__ __launch_bounds__(256) void naive_pairwise(
    const float* __restrict__ x, const float* __restrict__ ref,
    float* __restrict__ out)
{
    const int row = blockIdx.x >> 5;
    const int j = (blockIdx.x & 31) * 256 + threadIdx.x;
    const float* xr = x + (size_t)row * 1024;
    const float* rr = ref + (size_t)j * 1024;

    __shared__ float xs[1024];
    float part = 0.f;
    for (int k = threadIdx.x; k < 1024; k += 256) {
        float v = xr[k] + 1e-7f;
        xs[k] = v;
        part += v * v;
    }
    #pragma unroll
    for (int o = 32; o; o >>= 1) part += __shfl_xor(part, o, 64);
    __shared__ float red[4];
    if ((threadIdx.x & 63) == 0) red[threadIdx.x >> 6] = part;
    __syncthreads();
    const float ssx = red[0] + red[1] + red[2] + red[3];

    float ssr = 0.f, dot = 0.f;
    for (int k = 0; k < 1024; ++k) {
        float r = rr[k];
        ssr += r * r;
        dot += r * xs[k];
    }
    out[(size_t)row * 8192 + j] =
        dot * rsqrtf(fmaxf(ssx, 1e-12f)) * rsqrtf(fmaxf(ssr, 1e-12f));
}

extern "C" void kernel_launch(void* const* d_in, const int* in_sizes, int n_in,
                              void* d_out, int out_size, void* d_ws, size_t ws_size,
                              hipStream_t stream) {
    const float* x   = (const float*)d_in[0];   // [4,2048,1024] -> [8192][1024]
    const float* ref = (const float*)d_in[1];   // [8192][1024]
    float* out = (float*)d_out;                 // [8192][8192]

    const size_t need = (size_t)GM * GK * sizeof(__bf16) * 2;  // 32 MB
    if (ws_size >= need) {
        __bf16* wsA = (__bf16*)d_ws;
        __bf16* wsB = wsA + (size_t)GM * GK;
        normalize_rows<<<16384, 256, 0, stream>>>(x, ref, wsA, wsB);
        gemm_bt<<<(GM / BM) * (GN / BN), 256, 0, stream>>>(wsA, wsB, out);
    } else {
        naive_pairwise<<<8192 * 32, 256, 0, stream>>>(x, ref, out);
    }
}

// Round 2
// 177.719 us; speedup vs baseline: 1.2542x; 1.2542x over previous
//
#include <hip/hip_runtime.h>
#include <hip/hip_bf16.h>
#include <stdint.h>

typedef __bf16 bf16x8 __attribute__((ext_vector_type(8)));
typedef float f32x4 __attribute__((ext_vector_type(4)));

#define GLB_AS __attribute__((address_space(1)))
#define LDS_AS __attribute__((address_space(3)))

__device__ __forceinline__ void gload_lds16(const void* g, void* l) {
    // dest is wave-uniform base; HW writes base + lane*16
    __builtin_amdgcn_global_load_lds((GLB_AS void*)(g), (LDS_AS void*)(l), 16, 0, 0);
}

#define GM 8192
#define GN 8192
#define GK 1024
#define NT (GK / 64)   // 16 K-tiles of 64
#define NI (NT / 2)    // 8 iterations, 2 K-tiles each

// ---------------------------------------------------------------------------
// Kernel 1: row L2-normalize (x gets +1e-7 first), write bf16.
// ---------------------------------------------------------------------------
__global__ __launch_bounds__(256) void normalize_rows(
    const float* __restrict__ x, const float* __restrict__ ref,
    __bf16* __restrict__ outA, __bf16* __restrict__ outB)
{
    const int row = blockIdx.x;
    const bool isX = row < 8192;
    const size_t r = isX ? (size_t)row : (size_t)(row - 8192);
    const float* src = isX ? (x + r * 1024) : (ref + r * 1024);
    __bf16* dst = isX ? (outA + r * 1024) : (outB + r * 1024);
    const float eps = isX ? 1e-7f : 0.0f;

    const int t = threadIdx.x;
    float4 v = reinterpret_cast<const float4*>(src)[t];
    v.x += eps; v.y += eps; v.z += eps; v.w += eps;
    float ss = v.x * v.x + v.y * v.y + v.z * v.z + v.w * v.w;

    #pragma unroll
    for (int o = 32; o; o >>= 1) ss += __shfl_xor(ss, o, 64);

    __shared__ float red[4];
    const int wv = t >> 6, lane = t & 63;
    if (lane == 0) red[wv] = ss;
    __syncthreads();
    const float tot = red[0] + red[1] + red[2] + red[3];
    const float inv = rsqrtf(fmaxf(tot, 1e-12f));

    __bf16 b[4];
    b[0] = (__bf16)(v.x * inv);
    b[1] = (__bf16)(v.y * inv);
    b[2] = (__bf16)(v.z * inv);
    b[3] = (__bf16)(v.w * inv);
    uint2 pk;
    __builtin_memcpy(&pk, b, 8);
    reinterpret_cast<uint2*>(dst)[t] = pk;
}

// ---------------------------------------------------------------------------
// Kernel 2: 256x256 8-phase bf16 GEMM (C = A . B^T), plain-HIP HK-style.
//  - 512 thr = 8 waves (2M x 4N), per-wave 128x64 output, acc[8][4] f32x4
//  - LDS 128 KiB: As/Bs [2 buf][2 half][128][64], halves = quadrant row/col sets
//  - per phase: ds_read frags | stage 1 half-tile (2x gload_lds) | bar |
//               lgkmcnt(0) | setprio(1) 16x MFMA setprio(0) | bar
//  - counted vmcnt(6) at phases 4 and 8 only (3 half-tiles in flight)
//  - T2 swizzle: LDS slot s of row l holds global k-slot s^(l&7)
//    (inverse-swizzled global source, swizzled ds_read — rule #21)
// ---------------------------------------------------------------------------
__global__ __launch_bounds__(512, 2) void gemm_bt8(
    const __bf16* __restrict__ A, const __bf16* __restrict__ B,
    float* __restrict__ C)
{
    __shared__ __bf16 As[2][2][128][64];   // 64 KB
    __shared__ __bf16 Bs[2][2][128][64];   // 64 KB

    // XCD-bijective swizzle (1024 % 8 == 0), then 4x4 supertile for L2
    const int bid = blockIdx.x;
    const int swz = (bid & 7) * 128 + (bid >> 3);
    const int within = swz & 15;
    const int super  = swz >> 4;
    const int tm = (super & 7) * 4 + (within & 3);
    const int tn = (super >> 3) * 4 + (within >> 2);
    const size_t rowM0 = (size_t)tm * 256;
    const size_t rowN0 = (size_t)tn * 256;

    const int tid  = threadIdx.x;
    const int wave = tid >> 6;
    const int lane = tid & 63;
    const int wr = wave >> 2;      // 0..1
    const int wc = wave & 3;       // 0..3

    const int srow  = lane >> 3;            // staging: row within 8-row chunk
    const int sslot = (lane & 7) ^ srow;    // inverse-swizzled global k-slot
    const int fr = lane & 15;               // frag row
    const int fs = lane >> 4;               // frag k-subslot

    bf16x8 af[4][2];       // A frags: current qm, [m_local][ks]
    bf16x8 bq[2][2][2];    // B frags: both qn held, [qn][n_local][ks]
    f32x4  acc[8][4] = {};

// stage one A half-tile (128 LDS rows x 128 B): global row = j*128 + h*64 + r
#define STAGE_A(T, h, b) { \
    _Pragma("unroll") \
    for (int j = 0; j < 2; ++j) { \
        const size_t grow = rowM0 + (size_t)(j) * 128 + (h) * 64 + wave * 8 + srow; \
        const char* src = (const char*)A + (grow * GK + (size_t)(T) * 64) * 2 + sslot * 16; \
        char* dst = (char*)&As[b][h][0][0] + (j * 64 + wave * 8) * 128; \
        gload_lds16(src, dst); } }

// stage one B half-tile: LDS row l -> global B-row = (l>>5)*64 + h*32 + (l&31)
#define STAGE_B(T, h, b) { \
    _Pragma("unroll") \
    for (int j = 0; j < 2; ++j) { \
        const int l = j * 64 + wave * 8 + srow; \
        const size_t grow = rowN0 + (size_t)(l >> 5) * 64 + (h) * 32 + (l & 31); \
        const char* src = (const char*)B + (grow * GK + (size_t)(T) * 64) * 2 + sslot * 16; \
        char* dst = (char*)&Bs[b][h][0][0] + (j * 64 + wave * 8) * 128; \
        gload_lds16(src, dst); } }

#define LDA(qm, b) { \
    _Pragma("unroll") \
    for (int m = 0; m < 4; ++m) { \
        const int l = wr * 64 + m * 16 + fr; \
        _Pragma("unroll") \
        for (int ks = 0; ks < 2; ++ks) { \
            const int slot = (ks * 4 + fs) ^ (l & 7); \
            af[m][ks] = *(const bf16x8*)((const char*)&As[b][qm][0][0] + l * 128 + slot * 16); } } }

#define LDB(qn, b) { \
    _Pragma("unroll") \
    for (int n = 0; n < 2; ++n) { \
        const int l = wc * 32 + n * 16 + fr; \
        _Pragma("unroll") \
        for (int ks = 0; ks < 2; ++ks) { \
            const int slot = (ks * 4 + fs) ^ (l & 7); \
            bq[qn][n][ks] = *(const bf16x8*)((const char*)&Bs[b][qn][0][0] + l * 128 + slot * 16); } } }

#define QMFMA(qm, qn) { \
    __builtin_amdgcn_s_setprio(1); \
    _Pragma("unroll") \
    for (int ks = 0; ks < 2; ++ks) \
    _Pragma("unroll") \
    for (int m = 0; m < 4; ++m) \
    _Pragma("unroll") \
    for (int n = 0; n < 2; ++n) \
        acc[(qm) * 4 + m][(qn) * 2 + n] = __builtin_amdgcn_mfma_f32_16x16x32_bf16( \
            af[m][ks], bq[qn][n][ks], acc[(qm) * 4 + m][(qn) * 2 + n], 0, 0, 0); \
    __builtin_amdgcn_s_setprio(0); }

#define BAR() __builtin_amdgcn_s_barrier()
#define WAIT_LGKM0() { asm volatile("s_waitcnt lgkmcnt(0)" ::: "memory"); __builtin_amdgcn_sched_barrier(0); }
#define WAIT_VM(n)   { asm volatile("s_waitcnt vmcnt(" #n ")" ::: "memory"); __builtin_amdgcn_sched_barrier(0); }

    // prologue: tile0 fully, tile1 minus A-h1 (staged at phase 1)
    STAGE_A(0, 0, 0); STAGE_A(0, 1, 0); STAGE_B(0, 0, 0); STAGE_B(0, 1, 0);
    STAGE_A(1, 0, 1); STAGE_B(1, 0, 1); STAGE_B(1, 1, 1);
    WAIT_VM(6);
    BAR();

    #pragma unroll 1
    for (int i = 0; i < NI; ++i) {
        const int t1 = 2 * i + 1, t2 = 2 * i + 2, t3 = 2 * i + 3;
        const bool more = (i < NI - 1);

        // phase 1: Q(0,0) of tile t0 (buf0); stage t1 A-h1
        LDA(0, 0); LDB(0, 0);
        STAGE_A(t1, 1, 1);
        BAR(); WAIT_LGKM0();
        QMFMA(0, 0);
        BAR();
        // phase 2: Q(0,1); stage t2 A-h0 (A-h0 of t0 free after ph1)
        LDB(1, 0);
        if (more) STAGE_A(t2, 0, 0);
        BAR(); WAIT_LGKM0();
        QMFMA(0, 1);
        BAR();
        // phase 3: Q(1,0); stage t2 B-h0 (B-h0 of t0 read only at ph1)
        LDA(1, 0);
        if (more) STAGE_B(t2, 0, 0);
        BAR(); WAIT_LGKM0();
        QMFMA(1, 0);
        BAR();
        // phase 4: Q(1,1); stage t2 B-h1; counted vmcnt covers tile t1
        if (more) { STAGE_B(t2, 1, 0); WAIT_VM(6); }
        else      { WAIT_VM(0); }
        BAR();
        QMFMA(1, 1);
        BAR();
        // phase 5: Q(0,0) of tile t1 (buf1); stage t2 A-h1 (free after ph3)
        LDA(0, 1); LDB(0, 1);
        if (more) STAGE_A(t2, 1, 0);
        BAR(); WAIT_LGKM0();
        QMFMA(0, 0);
        BAR();
        // phase 6: Q(0,1); stage t3 A-h0 (A-h0 of t1 free after ph5)
        LDB(1, 1);
        if (more) STAGE_A(t3, 0, 1);
        BAR(); WAIT_LGKM0();
        QMFMA(0, 1);
        BAR();
        // phase 7: Q(1,0); stage t3 B-h0
        LDA(1, 1);
        if (more) STAGE_B(t3, 0, 1);
        BAR(); WAIT_LGKM0();
        QMFMA(1, 0);
        BAR();
        // phase 8: Q(1,1); stage t3 B-h1; counted vmcnt covers tile t2
        if (more) { STAGE_B(t3, 1, 1); WAIT_VM(6); }
        else      { WAIT_VM(0); }
        BAR();
        QMFMA(1, 1);
        BAR();
    }

    // epilogue: C/D layout col = lane&15, row = (lane>>4)*4 + j
    const size_t crow0 = rowM0 + (size_t)wr * 128;
    const size_t ccol0 = rowN0 + (size_t)wc * 64;
    #pragma unroll
    for (int mi = 0; mi < 8; ++mi) {
        #pragma unroll
        for (int ni = 0; ni < 4; ++ni) {
            const size_t col = ccol0 + ni * 16 + (lane & 15);
            const size_t rb  = crow0 + mi * 16 + (lane >> 4) * 4;
            #pragma unroll
            for (int j = 0; j < 4; ++j)
                C[(rb + j) * (size_t)GN + col] = acc[mi][ni][j];
        }
    }

#undef STAGE_A
#undef STAGE_B
#undef LDA
#undef LDB
#undef QMFMA
#undef BAR
#undef WAIT_LGKM0
#undef WAIT_VM
}

// ---------------------------------------------------------------------------
// Fallback (only if d_ws is too small): naive fp32, correct but slow.
// ---------------------------------------------------------------------------
__global__ __launch_bounds__(256) void naive_pairwise(
    const float* __restrict__ x, const float* __restrict__ ref,
    float* __restrict__ out)
{
    const int row = blockIdx.x >> 5;
    const int j = (blockIdx.x & 31) * 256 + threadIdx.x;
    const float* xr = x + (size_t)row * 1024;
    const float* rr = ref + (size_t)j * 1024;

    __shared__ float xs[1024];
    float part = 0.f;
    for (int k = threadIdx.x; k < 1024; k += 256) {
        float v = xr[k] + 1e-7f;
        xs[k] = v;
        part += v * v;
    }
    #pragma unroll
    for (int o = 32; o; o >>= 1) part += __shfl_xor(part, o, 64);
    __shared__ float red[4];
    if ((threadIdx.x & 63) == 0) red[threadIdx.x >> 6] = part;
    __syncthreads();
    const float ssx = red[0] + red[1] + red[2] + red[3];

    float ssr = 0.f, dot = 0.f;
    for (int k = 0; k < 1024; ++k) {
        float r = rr[k];
        ssr += r * r;
        dot += r * xs[k];
    }
    out[(size_t)row * 8192 + j] =
        dot * rsqrtf(fmaxf(ssx, 1e-12f)) * rsqrtf(fmaxf(ssr, 1e-12f));
}

extern "C" void kernel_launch(void* const* d_in, const int* in_sizes, int n_in,
                              void* d_out, int out_size, void* d_ws, size_t ws_size,
                              hipStream_t stream) {
    const float* x   = (const float*)d_in[0];   // [4,2048,1024] -> [8192][1024]
    const float* ref = (const float*)d_in[1];   // [8192][1024]
    float* out = (float*)d_out;                 // [8192][8192]

    const size_t need = (size_t)GM * GK * sizeof(__bf16) * 2;  // 32 MB
    if (ws_size >= need) {
        __bf16* wsA = (__bf16*)d_ws;
        __bf16* wsB = wsA + (size_t)GM * GK;
        normalize_rows<<<16384, 256, 0, stream>>>(x, ref, wsA, wsB);
        gemm_bt8<<<(GM / 256) * (GN / 256), 512, 0, stream>>>(wsA, wsB, out);
    } else {
        naive_pairwise<<<8192 * 32, 256, 0, stream>>>(x, ref, out);
    }
}